// Round 2
// baseline (301.082 us; speedup 1.0000x reference)
//
#include <hip/hip_runtime.h>
#include <hip/hip_bf16.h>

// f32 variant: reference dtypes are float32; ints are int32.
typedef __bf16 bf16;
typedef __bf16 bf16x8 __attribute__((ext_vector_type(8)));
typedef float f32x4 __attribute__((ext_vector_type(4)));

#define NB 32
#define SS 2048
#define NN 65536   // NB*SS
#define DD 512
#define HH 4
#define HD 128
#define TT 24

// ---------------- ws layout (byte offsets) ----------------
// su  f32 [H][B][T]          @ 0        (12288 B)
// st  f32 [H][T][T]          @ 12288    (9216 B)
// b2  f32 [544]              @ 21504    (2176 B)
// k   f32 [H][T][HD]         @ 23680    (49152 B)
// v   f32 [H][T][HD]         @ 72832    (49152 B)
// qt  f32 [H][T][HD]         @ 121984   (49152 B)
// qu  f32 [H][B][HD]         @ 171136   (65536 B)
// w2t bf16 [544][96]         @ 236672   (104448 B)   total ~333 KB

// Kernel A1: k, v, qt, qu  (53248 dot-of-512 tasks)
__global__ __launch_bounds__(256) void prep1(
    const float* __restrict__ tslot, const float* __restrict__ smooth,
    const int* __restrict__ user_x, const float* __restrict__ upref,
    const float* __restrict__ Wq, const float* __restrict__ bq,
    const float* __restrict__ Wk, const float* __restrict__ bk,
    const float* __restrict__ Wv, const float* __restrict__ bv,
    float* __restrict__ ws_k, float* __restrict__ ws_v,
    float* __restrict__ ws_qt, float* __restrict__ ws_qu)
{
    int gid = blockIdx.x * 256 + threadIdx.x;
    if (gid < 12288) {                       // k[h][t][e]
        int e = gid & 127; int th = gid >> 7; int t = th % TT; int h = th / TT;
        const float* x = smooth + t * DD;
        const float* w = Wk + (size_t)(h * DD) * HD + e;
        float acc = bk[h * HD + e];
        #pragma unroll 8
        for (int d = 0; d < DD; ++d) acc += x[d] * w[(size_t)d * HD];
        ws_k[gid] = acc;
    } else if (gid < 24576) {                // v[h][t][e]
        int idx = gid - 12288;
        int e = idx & 127; int th = idx >> 7; int t = th % TT; int h = th / TT;
        const float* x = smooth + t * DD;
        const float* w = Wv + (size_t)(h * DD) * HD + e;
        float acc = bv[h * HD + e];
        #pragma unroll 8
        for (int d = 0; d < DD; ++d) acc += x[d] * w[(size_t)d * HD];
        ws_v[idx] = acc;
    } else if (gid < 36864) {                // qt[h][t][e] (time half of Wq, +bq)
        int idx = gid - 24576;
        int e = idx & 127; int th = idx >> 7; int t = th % TT; int h = th / TT;
        const float* x = tslot + t * DD;
        const float* w = Wq + (size_t)(h * 2 * DD + DD) * HD + e;
        float acc = bq[h * HD + e];
        #pragma unroll 8
        for (int d = 0; d < DD; ++d) acc += x[d] * w[(size_t)d * HD];
        ws_qt[idx] = acc;
    } else {                                 // qu[h][b][e] (user half of Wq)
        int idx = gid - 36864;               // < 16384
        int e = idx & 127; int b = (idx >> 7) & 31; int h = idx >> 12;
        const float* x = upref + (size_t)user_x[b] * DD;
        const float* w = Wq + (size_t)(h * 2 * DD) * HD + e;
        float acc = 0.f;
        #pragma unroll 8
        for (int d = 0; d < DD; ++d) acc += x[d] * w[(size_t)d * HD];
        ws_qu[idx] = acc;
    }
}

// Kernel A2: su, st, W2T, b2 (needs A1 results)
__global__ __launch_bounds__(256) void prep2(
    const float* __restrict__ ws_k, const float* __restrict__ ws_v,
    const float* __restrict__ ws_qt, const float* __restrict__ ws_qu,
    const float* __restrict__ Wu, const float* __restrict__ bu,
    const float* __restrict__ Wt, const float* __restrict__ bt,
    float* __restrict__ ws_su, float* __restrict__ ws_st,
    float* __restrict__ ws_b2, bf16* __restrict__ ws_w2t)
{
    int gid = blockIdx.x * 256 + threadIdx.x;
    if (gid < 3072) {                        // su[h][b][t'] = qu . k
        int tp = gid % TT; int hb = gid / TT; // hb = h*32+b
        const float* q = ws_qu + hb * HD;
        int h = hb >> 5;
        const float* kk = ws_k + (h * TT + tp) * HD;
        float acc = 0.f;
        #pragma unroll 8
        for (int e = 0; e < HD; ++e) acc += q[e] * kk[e];
        ws_su[gid] = acc;
    } else if (gid < 5376) {                 // st[h][t][t'] = qt . k
        int idx = gid - 3072;
        int tp = idx % TT; int ht = idx / TT; int h = ht / TT;
        const float* q = ws_qt + ht * HD;
        const float* kk = ws_k + (h * TT + tp) * HD;
        float acc = 0.f;
        #pragma unroll 8
        for (int e = 0; e < HD; ++e) acc += q[e] * kk[e];
        ws_st[idx] = acc;
    } else if (gid < 5376 + 52224) {         // w2t[j][i], i=h*24+t, j in [0,544)
        int idx = gid - 5376;
        int i = idx % 96; int j = idx / 96;
        int h = i / TT;
        const float* vv = ws_v + i * HD;
        float acc = 0.f;
        if (j < 512) {
            const float* w = Wu + (size_t)(h * HD) * DD + j;
            #pragma unroll 8
            for (int e = 0; e < HD; ++e) acc += vv[e] * w[(size_t)e * DD];
        } else if (j < 536) {
            const float* w = Wt + (size_t)(h * HD) * TT + (j - 512);
            #pragma unroll 8
            for (int e = 0; e < HD; ++e) acc += vv[e] * w[(size_t)e * TT];
        }
        ws_w2t[j * 96 + i] = (bf16)acc;
    } else if (gid < 5376 + 52224 + 544) {   // b2[j]
        int j = gid - (5376 + 52224);
        float val = (j < 512) ? bu[j] : ((j < 536) ? bt[j - 512] : 0.f);
        ws_b2[j] = val;
    }
}

// Main fused kernel: 64 rows/block. Phase 1: attn[64][96] in LDS (bf16).
// Phase 2: [64x96] @ [96x544] via mfma_f32_16x16x32_bf16.
__global__ __launch_bounds__(256) void fused_main(
    const int* __restrict__ hour_x, const int* __restrict__ hour_mask,
    const float* __restrict__ osc_u, const float* __restrict__ osc_v,
    const float* __restrict__ ws_su, const float* __restrict__ ws_st,
    const float* __restrict__ ws_b2, const bf16* __restrict__ ws_w2t,
    float* __restrict__ out_at, float* __restrict__ out_tl)
{
    __shared__ bf16 attn_lds[64][104];       // 96 used, stride 104 (16B-aligned rows)

    const int tid = threadIdx.x;
    const int h = tid >> 6;                  // wave-uniform head
    const int r = tid & 63;
    const int n0 = blockIdx.x * 64;
    const int n = n0 + r;
    const int b = n >> 11;                   // S = 2048
    const int hour = hour_x[n];

    const float* su = ws_su + (h * NB + b) * TT;
    const float* st = ws_st + (h * TT + hour) * TT;
    const int*   mk = hour_mask + (size_t)n * TT;
    const float* up = osc_u + (size_t)(h * NN + n) * TT;
    const float* vp = osc_v + (size_t)(h * NN + n) * TT;

    float ub[24], vb[24], sub[24], stb[24];
    int mb[24];
    #pragma unroll
    for (int i = 0; i < 6; ++i) {
        *(float4*)(ub + i * 4)  = *(const float4*)(up + i * 4);
        *(float4*)(vb + i * 4)  = *(const float4*)(vp + i * 4);
        *(int4*)(mb + i * 4)    = *(const int4*)(mk + i * 4);
        *(float4*)(sub + i * 4) = *(const float4*)(su + i * 4);
        *(float4*)(stb + i * 4) = *(const float4*)(st + i * 4);
    }

    float z[24];
    float mx = -3.4e38f;
    #pragma unroll
    for (int t = 0; t < 24; ++t) {
        float s = (sub[t] + stb[t]) * 0.08838834764831845f;   // 1/sqrt(128)
        float du = 0.01f * ub[t] - 0.01f * vb[t];
        float g = __expf(-500.0f * s * s);
        float zz = du * g + fmaxf(s, 0.0f);
        zz = (mb[t] == 1) ? 0.0f : zz;       // masked: s=-inf => z=0 exactly
        z[t] = zz;
        mx = fmaxf(mx, zz);
    }
    float ssum = 0.f;
    #pragma unroll
    for (int t = 0; t < 24; ++t) { float p = __expf(z[t] - mx); z[t] = p; ssum += p; }
    float inv = 1.0f / ssum;
    #pragma unroll
    for (int t = 0; t < 24; ++t) attn_lds[r][h * TT + t] = (bf16)(z[t] * inv);

    __syncthreads();

    // ---- phase 2: MFMA GEMM attn[64][96] @ W2T^T[96][544] ----
    const int w    = tid >> 6;
    const int lane = tid & 63;
    const int m16  = lane & 15;
    const int quad = lane >> 4;

    for (int ct = w; ct < 34; ct += 4) {
        const int c0 = ct * 16;
        const int c  = c0 + m16;             // output column, < 544
        bf16x8 bfr[3];
        #pragma unroll
        for (int kk = 0; kk < 3; ++kk)
            bfr[kk] = *(const bf16x8*)(ws_w2t + c * 96 + kk * 32 + quad * 8);
        const float bias = ws_b2[c];

        #pragma unroll
        for (int rt = 0; rt < 4; ++rt) {
            f32x4 acc = {0.f, 0.f, 0.f, 0.f};
            #pragma unroll
            for (int kk = 0; kk < 3; ++kk) {
                bf16x8 afr = *(const bf16x8*)(&attn_lds[rt * 16 + m16][kk * 32 + quad * 8]);
                acc = __builtin_amdgcn_mfma_f32_16x16x32_bf16(afr, bfr[kk], acc, 0, 0, 0);
            }
            #pragma unroll
            for (int reg = 0; reg < 4; ++reg) {
                const int gr = n0 + rt * 16 + quad * 4 + reg;
                const float val = acc[reg] + bias;
                if (c < 512)      out_at[(size_t)gr * DD + c] = val;
                else if (c < 536) out_tl[(size_t)gr * TT + (c - 512)] = val;
            }
        }
    }
}

extern "C" void kernel_launch(void* const* d_in, const int* in_sizes, int n_in,
                              void* d_out, int out_size, void* d_ws, size_t ws_size,
                              hipStream_t stream)
{
    const float* tslot  = (const float*)d_in[0];
    const float* smooth = (const float*)d_in[1];
    // d_in[2] user_embedded: unused by the reference
    const int*  user_x = (const int*)d_in[3];
    const int*  hour_x = (const int*)d_in[4];
    const int*  hour_mask = (const int*)d_in[5];
    const float* upref  = (const float*)d_in[6];
    const float* Wq = (const float*)d_in[7];
    const float* bq = (const float*)d_in[8];
    const float* Wk = (const float*)d_in[9];
    const float* bk = (const float*)d_in[10];
    const float* Wv = (const float*)d_in[11];
    const float* bv = (const float*)d_in[12];
    const float* Wu = (const float*)d_in[13];
    const float* bu = (const float*)d_in[14];
    const float* Wt = (const float*)d_in[15];
    const float* bt = (const float*)d_in[16];
    const float* osc_u = (const float*)d_in[17];
    const float* osc_v = (const float*)d_in[18];

    char* ws = (char*)d_ws;
    float* ws_su = (float*)(ws + 0);
    float* ws_st = (float*)(ws + 12288);
    float* ws_b2 = (float*)(ws + 21504);
    float* ws_k  = (float*)(ws + 23680);
    float* ws_v  = (float*)(ws + 72832);
    float* ws_qt = (float*)(ws + 121984);
    float* ws_qu = (float*)(ws + 171136);
    bf16*  ws_w2t = (bf16*)(ws + 236672);

    float* out_at = (float*)d_out;
    float* out_tl = out_at + (size_t)NN * DD;

    prep1<<<208, 256, 0, stream>>>(tslot, smooth, user_x, upref, Wq, bq, Wk, bk,
                                   Wv, bv, ws_k, ws_v, ws_qt, ws_qu);
    prep2<<<228, 256, 0, stream>>>(ws_k, ws_v, ws_qt, ws_qu, Wu, bu, Wt, bt,
                                   ws_su, ws_st, ws_b2, ws_w2t);
    fused_main<<<NN / 64, 256, 0, stream>>>(hour_x, hour_mask, osc_u, osc_v,
                                            ws_su, ws_st, ws_b2, ws_w2t,
                                            out_at, out_tl);
}

// Round 3
// 294.942 us; speedup vs baseline: 1.0208x; 1.0208x over previous
//
#include <hip/hip_runtime.h>
#include <hip/hip_bf16.h>

// f32 variant: reference dtypes are float32; ints are int32.
typedef __bf16 bf16;
typedef __bf16 bf16x8 __attribute__((ext_vector_type(8)));
typedef float f32x4 __attribute__((ext_vector_type(4)));

#define NB 32
#define SS 2048
#define NN 65536   // NB*SS
#define DD 512
#define HH 4
#define HD 128
#define TT 24

// ---------------- ws layout (byte offsets) ----------------
// su  f32 [H][B][T]          @ 0        (12288 B)
// st  f32 [H][T][T]          @ 12288    (9216 B)
// b2  f32 [544]              @ 21504    (2176 B)
// k   f32 [H][T][HD]         @ 23680    (49152 B)
// v   f32 [H][T][HD]         @ 72832    (49152 B)
// qt  f32 [H][T][HD]         @ 121984   (49152 B)
// qu  f32 [H][B][HD]         @ 171136   (65536 B)
// w2t bf16 [544][96]         @ 236672   (104448 B)   total ~333 KB

// Kernel A1: k, v, qt, qu  (53248 dot-of-512 tasks).
// 4 independent accumulators: 128-deep chains instead of 512-deep.
__global__ __launch_bounds__(256) void prep1(
    const float* __restrict__ tslot, const float* __restrict__ smooth,
    const int* __restrict__ user_x, const float* __restrict__ upref,
    const float* __restrict__ Wq, const float* __restrict__ bq,
    const float* __restrict__ Wk, const float* __restrict__ bk,
    const float* __restrict__ Wv, const float* __restrict__ bv,
    float* __restrict__ ws_k, float* __restrict__ ws_v,
    float* __restrict__ ws_qt, float* __restrict__ ws_qu)
{
    int gid = blockIdx.x * 256 + threadIdx.x;
    const float* x; const float* w; float acc;
    float* dst;
    if (gid < 12288) {                       // k[h][t][e]
        int e = gid & 127; int th = gid >> 7; int t = th % TT; int h = th / TT;
        x = smooth + t * DD;
        w = Wk + (size_t)(h * DD) * HD + e;
        acc = bk[h * HD + e];
        dst = ws_k + gid;
    } else if (gid < 24576) {                // v[h][t][e]
        int idx = gid - 12288;
        int e = idx & 127; int th = idx >> 7; int t = th % TT; int h = th / TT;
        x = smooth + t * DD;
        w = Wv + (size_t)(h * DD) * HD + e;
        acc = bv[h * HD + e];
        dst = ws_v + idx;
    } else if (gid < 36864) {                // qt[h][t][e] (time half of Wq, +bq)
        int idx = gid - 24576;
        int e = idx & 127; int th = idx >> 7; int t = th % TT; int h = th / TT;
        x = tslot + t * DD;
        w = Wq + (size_t)(h * 2 * DD + DD) * HD + e;
        acc = bq[h * HD + e];
        dst = ws_qt + idx;
    } else {                                 // qu[h][b][e] (user half of Wq)
        int idx = gid - 36864;               // < 16384
        int e = idx & 127; int b = (idx >> 7) & 31; int h = idx >> 12;
        x = upref + (size_t)user_x[b] * DD;
        w = Wq + (size_t)(h * 2 * DD) * HD + e;
        acc = 0.f;
        dst = ws_qu + idx;
    }
    float a0 = 0.f, a1 = 0.f, a2 = 0.f, a3 = 0.f;
    #pragma unroll 4
    for (int d = 0; d < 128; ++d) {
        a0 += x[d]       * w[(size_t)(d)       * HD];
        a1 += x[d + 128] * w[(size_t)(d + 128) * HD];
        a2 += x[d + 256] * w[(size_t)(d + 256) * HD];
        a3 += x[d + 384] * w[(size_t)(d + 384) * HD];
    }
    *dst = acc + ((a0 + a1) + (a2 + a3));
}

// Kernel A2: su, st, W2T, b2 (needs A1 results)
__global__ __launch_bounds__(256) void prep2(
    const float* __restrict__ ws_k, const float* __restrict__ ws_v,
    const float* __restrict__ ws_qt, const float* __restrict__ ws_qu,
    const float* __restrict__ Wu, const float* __restrict__ bu,
    const float* __restrict__ Wt, const float* __restrict__ bt,
    float* __restrict__ ws_su, float* __restrict__ ws_st,
    float* __restrict__ ws_b2, bf16* __restrict__ ws_w2t)
{
    int gid = blockIdx.x * 256 + threadIdx.x;
    if (gid < 3072) {                        // su[h][b][t'] = qu . k
        int tp = gid % TT; int hb = gid / TT; // hb = h*32+b
        const float* q = ws_qu + hb * HD;
        int h = hb >> 5;
        const float* kk = ws_k + (h * TT + tp) * HD;
        float acc = 0.f;
        #pragma unroll 8
        for (int e = 0; e < HD; ++e) acc += q[e] * kk[e];
        ws_su[gid] = acc;
    } else if (gid < 5376) {                 // st[h][t][t'] = qt . k
        int idx = gid - 3072;
        int tp = idx % TT; int ht = idx / TT; int h = ht / TT;
        const float* q = ws_qt + ht * HD;
        const float* kk = ws_k + (h * TT + tp) * HD;
        float acc = 0.f;
        #pragma unroll 8
        for (int e = 0; e < HD; ++e) acc += q[e] * kk[e];
        ws_st[idx] = acc;
    } else if (gid < 5376 + 52224) {         // w2t[j][i], i=h*24+t, j in [0,544)
        int idx = gid - 5376;
        int i = idx % 96; int j = idx / 96;
        int h = i / TT;
        const float* vv = ws_v + i * HD;
        float acc = 0.f;
        if (j < 512) {
            const float* w = Wu + (size_t)(h * HD) * DD + j;
            #pragma unroll 8
            for (int e = 0; e < HD; ++e) acc += vv[e] * w[(size_t)e * DD];
        } else if (j < 536) {
            const float* w = Wt + (size_t)(h * HD) * TT + (j - 512);
            #pragma unroll 8
            for (int e = 0; e < HD; ++e) acc += vv[e] * w[(size_t)e * TT];
        }
        ws_w2t[j * 96 + i] = (bf16)acc;
    } else if (gid < 5376 + 52224 + 544) {   // b2[j]
        int j = gid - (5376 + 52224);
        float val = (j < 512) ? bu[j] : ((j < 536) ? bt[j - 512] : 0.f);
        ws_b2[j] = val;
    }
}

// Main fused kernel: 64 rows/block. Phase 1: attn[64][96] in LDS (bf16).
// Phase 2: [64x96] @ [96x544] via mfma_f32_16x16x32_bf16 with SWAPPED
// operands: D-tile = (W2T x attn^T), so lane's 4 acc regs are 4 consecutive
// OUTPUT COLUMNS of one row -> global_store_dwordx4 epilogue.
__global__ __launch_bounds__(256) void fused_main(
    const int* __restrict__ hour_x, const int* __restrict__ hour_mask,
    const float* __restrict__ osc_u, const float* __restrict__ osc_v,
    const float* __restrict__ ws_su, const float* __restrict__ ws_st,
    const float* __restrict__ ws_b2, const bf16* __restrict__ ws_w2t,
    float* __restrict__ out_at, float* __restrict__ out_tl)
{
    __shared__ bf16 attn_lds[64][104];       // 96 used, stride 104 (16B-aligned rows)

    const int tid = threadIdx.x;
    const int h = tid >> 6;                  // wave-uniform head
    const int r = tid & 63;
    const int n0 = blockIdx.x * 64;
    const int n = n0 + r;
    const int b = n >> 11;                   // S = 2048
    const int hour = hour_x[n];

    const float* su = ws_su + (h * NB + b) * TT;
    const float* st = ws_st + (h * TT + hour) * TT;
    const int*   mk = hour_mask + (size_t)n * TT;
    const float* up = osc_u + (size_t)(h * NN + n) * TT;
    const float* vp = osc_v + (size_t)(h * NN + n) * TT;

    float ub[24], vb[24], sub[24], stb[24];
    int mb[24];
    #pragma unroll
    for (int i = 0; i < 6; ++i) {
        *(float4*)(ub + i * 4)  = *(const float4*)(up + i * 4);
        *(float4*)(vb + i * 4)  = *(const float4*)(vp + i * 4);
        *(int4*)(mb + i * 4)    = *(const int4*)(mk + i * 4);
        *(float4*)(sub + i * 4) = *(const float4*)(su + i * 4);
        *(float4*)(stb + i * 4) = *(const float4*)(st + i * 4);
    }

    float z[24];
    float mx = -3.4e38f;
    #pragma unroll
    for (int t = 0; t < 24; ++t) {
        float s = (sub[t] + stb[t]) * 0.08838834764831845f;   // 1/sqrt(128)
        float du = 0.01f * ub[t] - 0.01f * vb[t];
        float g = __expf(-500.0f * s * s);
        float zz = du * g + fmaxf(s, 0.0f);
        zz = (mb[t] == 1) ? 0.0f : zz;       // masked: s=-inf => z=0 exactly
        z[t] = zz;
        mx = fmaxf(mx, zz);
    }
    float ssum = 0.f;
    #pragma unroll
    for (int t = 0; t < 24; ++t) { float p = __expf(z[t] - mx); z[t] = p; ssum += p; }
    float inv = 1.0f / ssum;

    // pack 24 bf16 and write as 3 x ds_write_b128
    bf16x8 pk[3];
    #pragma unroll
    for (int i = 0; i < 3; ++i)
        #pragma unroll
        for (int j = 0; j < 8; ++j) pk[i][j] = (bf16)(z[i * 8 + j] * inv);
    #pragma unroll
    for (int i = 0; i < 3; ++i)
        *(bf16x8*)(&attn_lds[r][h * TT + i * 8]) = pk[i];

    __syncthreads();

    // ---- phase 2: transposed-output MFMA GEMM ----
    const int w    = tid >> 6;
    const int lane = tid & 63;
    const int m16  = lane & 15;
    const int quad = lane >> 4;

    for (int ct = w; ct < 34; ct += 4) {
        const int c0 = ct * 16;
        const int cA = c0 + m16;             // W2T row (output column) for A-frag
        bf16x8 afr[3];
        #pragma unroll
        for (int kk = 0; kk < 3; ++kk)
            afr[kk] = *(const bf16x8*)(ws_w2t + cA * 96 + kk * 32 + quad * 8);
        const int cc0 = c0 + quad * 4;       // first of this lane's 4 output cols
        f32x4 bias4 = *(const f32x4*)(ws_b2 + cc0);

        #pragma unroll
        for (int rt = 0; rt < 4; ++rt) {
            f32x4 acc = {0.f, 0.f, 0.f, 0.f};
            #pragma unroll
            for (int kk = 0; kk < 3; ++kk) {
                bf16x8 bfr = *(const bf16x8*)(&attn_lds[rt * 16 + m16][kk * 32 + quad * 8]);
                acc = __builtin_amdgcn_mfma_f32_16x16x32_bf16(afr[kk], bfr, acc, 0, 0, 0);
            }
            const int row = n0 + rt * 16 + m16;   // D col (lane&15) = attn row
            f32x4 outv = acc + bias4;
            if (cc0 < 512) {
                __builtin_nontemporal_store(outv, (f32x4*)(out_at + (size_t)row * DD + cc0));
            } else if (cc0 < 536) {
                __builtin_nontemporal_store(outv, (f32x4*)(out_tl + (size_t)row * TT + (cc0 - 512)));
            }
        }
    }
}

extern "C" void kernel_launch(void* const* d_in, const int* in_sizes, int n_in,
                              void* d_out, int out_size, void* d_ws, size_t ws_size,
                              hipStream_t stream)
{
    const float* tslot  = (const float*)d_in[0];
    const float* smooth = (const float*)d_in[1];
    // d_in[2] user_embedded: unused by the reference
    const int*  user_x = (const int*)d_in[3];
    const int*  hour_x = (const int*)d_in[4];
    const int*  hour_mask = (const int*)d_in[5];
    const float* upref  = (const float*)d_in[6];
    const float* Wq = (const float*)d_in[7];
    const float* bq = (const float*)d_in[8];
    const float* Wk = (const float*)d_in[9];
    const float* bk = (const float*)d_in[10];
    const float* Wv = (const float*)d_in[11];
    const float* bv = (const float*)d_in[12];
    const float* Wu = (const float*)d_in[13];
    const float* bu = (const float*)d_in[14];
    const float* Wt = (const float*)d_in[15];
    const float* bt = (const float*)d_in[16];
    const float* osc_u = (const float*)d_in[17];
    const float* osc_v = (const float*)d_in[18];

    char* ws = (char*)d_ws;
    float* ws_su = (float*)(ws + 0);
    float* ws_st = (float*)(ws + 12288);
    float* ws_b2 = (float*)(ws + 21504);
    float* ws_k  = (float*)(ws + 23680);
    float* ws_v  = (float*)(ws + 72832);
    float* ws_qt = (float*)(ws + 121984);
    float* ws_qu = (float*)(ws + 171136);
    bf16*  ws_w2t = (bf16*)(ws + 236672);

    float* out_at = (float*)d_out;
    float* out_tl = out_at + (size_t)NN * DD;

    prep1<<<208, 256, 0, stream>>>(tslot, smooth, user_x, upref, Wq, bq, Wk, bk,
                                   Wv, bv, ws_k, ws_v, ws_qt, ws_qu);
    prep2<<<228, 256, 0, stream>>>(ws_k, ws_v, ws_qt, ws_qu, Wu, bu, Wt, bt,
                                   ws_su, ws_st, ws_b2, ws_w2t);
    fused_main<<<NN / 64, 256, 0, stream>>>(hour_x, hour_mask, osc_u, osc_v,
                                            ws_su, ws_st, ws_b2, ws_w2t,
                                            out_at, out_tl);
}